// Round 6
// baseline (218.699 us; speedup 1.0000x reference)
//
#include <hip/hip_runtime.h>
#include <cstddef>

#define N_TOK 4096
#define C_DIM 768
#define H_NUM 12
#define C3    2304
#define NSPL  4

typedef unsigned short u16;
using short8  = __attribute__((ext_vector_type(8))) short;
using floatx4 = __attribute__((ext_vector_type(4))) float;
using u16x4   = __attribute__((ext_vector_type(4))) u16;
using uint2v  = __attribute__((ext_vector_type(2))) unsigned;

#define K2SCALE 0.18033688011112043f  // (1/8) * log2(e), folded into Q at QKV epilogue

__device__ __forceinline__ u16 f2bf(float f) {
  union { float f; unsigned u; } v; v.f = f;
  unsigned r = v.u + 0x7FFFu + ((v.u >> 16) & 1u);
  return (u16)(r >> 16);
}

// truncate-pack two f32 -> two bf16 in one u32 (bias cancels: l uses same P~)
__device__ __forceinline__ unsigned permpack(float a, float b) {
  union { float f; unsigned u; } x, y; x.f = a; y.f = b;
  return __builtin_amdgcn_perm(y.u, x.u, 0x07060302u);
}

// bare v_exp_f32 (libcall exp2f adds denormal-guard VALU; inputs are range-safe)
__device__ __forceinline__ float aexp2(float x) {
  float r;
  asm("v_exp_f32 %0, %1" : "=v"(r) : "v"(x));
  return r;
}

__device__ __forceinline__ float arcp(float x) {
  float r;
  asm("v_rcp_f32 %0, %1" : "=v"(r) : "v"(x));
  return r;
}

// async global->LDS, 16B per lane. LDS dest must be wave-uniform base + lane*16.
__device__ __forceinline__ void gload_lds16(const void* g, void* l) {
  __builtin_amdgcn_global_load_lds(
      (const __attribute__((address_space(1))) unsigned int*)g,
      (__attribute__((address_space(3))) unsigned int*)l, 16, 0, 0);
}

// ---------- fused preprocessing: x f32->bf16 + both weight transpose/converts ----------
__global__ void k_pre(const float* __restrict__ x, u16* __restrict__ xb,
                      const float* __restrict__ wq, u16* __restrict__ wqT,
                      const float* __restrict__ wp, u16* __restrict__ wpT) {
  __shared__ float tile[32][33];
  const int b = blockIdx.x;
  if (b < 3072) {
    int i = b * 256 + threadIdx.x;
    float4 f = ((const float4*)x)[i];
    u16x4 o;
    o[0] = f2bf(f.x); o[1] = f2bf(f.y); o[2] = f2bf(f.z); o[3] = f2bf(f.w);
    ((u16x4*)xb)[i] = o;
    return;
  }
  const float* in; u16* out; int Cc, bx, by;
  if (b < 4800) { int t = b - 3072; in = wq; out = wqT; Cc = 2304; bx = t % 72; by = t / 72; }
  else          { int t = b - 4800; in = wp; out = wpT; Cc = 768;  bx = t % 24; by = t / 24; }
  const int R = 768;
  const int tx = threadIdx.x & 31;
  const int ty = threadIdx.x >> 5;
  const int c0 = bx * 32, r0 = by * 32;
#pragma unroll
  for (int i = 0; i < 32; i += 8)
    tile[ty + i][tx] = in[(size_t)(r0 + ty + i) * Cc + c0 + tx];
  __syncthreads();
#pragma unroll
  for (int i = 0; i < 32; i += 8)
    out[(size_t)(c0 + ty + i) * R + r0 + tx] = f2bf(tile[tx][ty + i]);
}

// ---------------- GEMM: C[M][N] = A[M][K] * B^T ( B stored [N][K] ) + bias ----------------
template <int MODE>
__global__ __launch_bounds__(256)
void k_gemm_bt(const u16* __restrict__ A, const u16* __restrict__ B,
               const float* __restrict__ bias, void* __restrict__ outp,
               u16* __restrict__ vT, int K) {
  __shared__ u16 As[128 * 32];
  __shared__ u16 Bs[128 * 32];
  const int tid  = threadIdx.x;
  const int wave = tid >> 6, lane = tid & 63, quad = lane >> 4, l16 = lane & 15;
  const int wrow = wave >> 1, wcol = wave & 1;
  const int bm = blockIdx.y, bn = blockIdx.x;
  const int r3 = l16 & 3;

  floatx4 acc[4][4];
#pragma unroll
  for (int i = 0; i < 4; ++i)
#pragma unroll
    for (int j = 0; j < 4; ++j)
#pragma unroll
      for (int r = 0; r < 4; ++r) acc[i][j][r] = 0.f;

  const int ar = tid >> 2;
  const int ac = ((tid & 3) ^ (ar & 3)) * 8;
  const u16* gA = A + (size_t)(bm * 128 + ar) * K + ac;
  const u16* gB = B + (size_t)(bn * 128 + ar) * K + ac;
  u16* lA = &As[0] + tid * 8;
  u16* lB = &Bs[0] + tid * 8;

  for (int k0 = 0; k0 < K; k0 += 32) {
    gload_lds16(gA + k0,                  lA);
    gload_lds16(gA + k0 + (size_t)64 * K, lA + 2048);
    gload_lds16(gB + k0,                  lB);
    gload_lds16(gB + k0 + (size_t)64 * K, lB + 2048);
    __syncthreads();
    short8 af[4], bf[4];
#pragma unroll
    for (int t = 0; t < 4; ++t) {
      af[t] = *(const short8*)&As[(wrow * 64 + t * 16 + l16) * 32 + ((quad ^ r3) * 8)];
      bf[t] = *(const short8*)&Bs[(wcol * 64 + t * 16 + l16) * 32 + ((quad ^ r3) * 8)];
    }
#pragma unroll
    for (int tm = 0; tm < 4; ++tm)
#pragma unroll
      for (int tn = 0; tn < 4; ++tn)
        acc[tm][tn] = __builtin_amdgcn_mfma_f32_16x16x32_bf16(af[tm], bf[tn], acc[tm][tn], 0, 0, 0);
    __syncthreads();
  }

  if (MODE == 0) {
    u16* qkv = (u16*)outp;
    const float qs = (bn < 6) ? K2SCALE : 1.0f;
#pragma unroll
    for (int tn = 0; tn < 4; ++tn) {
      const int col = bn * 128 + wcol * 64 + tn * 16 + l16;
      const float bc = bias[col];
      if (col < 1536) {
#pragma unroll
        for (int tm = 0; tm < 4; ++tm) {
          const int rowb = bm * 128 + wrow * 64 + tm * 16 + quad * 4;
#pragma unroll
          for (int r = 0; r < 4; ++r)
            qkv[(size_t)(rowb + r) * C3 + col] = f2bf((acc[tm][tn][r] + bc) * qs);
        }
      } else {
        const int hd_ = col - 1536;
#pragma unroll
        for (int tm = 0; tm < 4; ++tm) {
          const int rowb = bm * 128 + wrow * 64 + tm * 16 + quad * 4;
          u16x4 pk;
#pragma unroll
          for (int r = 0; r < 4; ++r) pk[r] = f2bf(acc[tm][tn][r] + bc);
          *(u16x4*)&vT[(size_t)hd_ * N_TOK + rowb] = pk;
        }
      }
    }
  } else {
    float* out = (float*)outp;
#pragma unroll
    for (int tn = 0; tn < 4; ++tn) {
      const int col = bn * 128 + wcol * 64 + tn * 16 + l16;
      const float bc = bias[col];
#pragma unroll
      for (int tm = 0; tm < 4; ++tm) {
        const int rowb = bm * 128 + wrow * 64 + tm * 16 + quad * 4;
#pragma unroll
        for (int r = 0; r < 4; ++r)
          out[(size_t)(rowb + r) * C_DIM + col] = acc[tm][tn][r] + bc;
      }
    }
  }
}

// ---------------- flash attention v5: q_w=64, split-K=4, half-K P buffer ----------------
// grid (16,12,4): qt(256 q-rows/block), head, split. Block 256 thr = 4 waves; wave owns
// 64 q-rows (4 subtiles of 16). Fixed-max softmax (Q pre-scaled -> P = exp2(S)).
// K-tile processed as two 32-k halves; wave-private P buffer (4 KB) reused per half
// (DS pipe is in-order per wave -> RAW through LDS is safe without barrier).
// LDS: K/V dbuf 32 KB + 4x4 KB P = 48 KB -> 3 blocks/CU = 12 waves/CU.
// ak/bv fragment reads amortize over 4 q-subtiles: ~8.8 B LDS per S-element.
__global__ __launch_bounds__(256)
void k_flash(const u16* __restrict__ qkv, const u16* __restrict__ vT,
             float* __restrict__ Opart, float* __restrict__ lpart) {
  __shared__ u16 Ks[2][64 * 64];
  __shared__ u16 Vs[2][64 * 64];   // Vs[d][m]
  __shared__ u16 Ps[4][64 * 32];   // per-wave P[qrow 0..63][k-half 0..31], swizzled
  const int tid  = threadIdx.x;
  const int wave = tid >> 6, lane = tid & 63, quad = lane >> 4, l16 = lane & 15;
  const int qt = blockIdx.x, h = blockIdx.y, split = blockIdx.z;
  const int lr = tid >> 3;                     // 0..31 (32 rows per DMA pass)
  const int lc = ((tid & 7) ^ (lr & 7)) * 8;   // swizzled source chunk
  const int r7 = l16 & 7;
  const int r3 = l16 & 3;
  const int kb = split * (N_TOK / NSPL);
  const int nt = (N_TOK / NSPL) / 64;          // 16 k-tiles

  // Q fragments (B-operand) straight from global: bq[qs][dh]
  short8 bq[4][2];
#pragma unroll
  for (int qs = 0; qs < 4; ++qs)
#pragma unroll
    for (int dh = 0; dh < 2; ++dh)
      bq[qs][dh] = *(const short8*)&qkv[(size_t)(qt * 256 + wave * 64 + qs * 16 + l16) * C3
                                        + h * 64 + dh * 32 + quad * 8];

  const u16* gk = qkv + (size_t)lr * C3 + C_DIM + h * 64 + lc;
  const u16* gv = vT + (size_t)(h * 64 + lr) * N_TOK + lc;

  auto stage = [&](int b, int m0) {
#pragma unroll
    for (int p = 0; p < 2; ++p) {
      gload_lds16(gk + (size_t)(m0 + p * 32) * C3,    &Ks[b][p * 2048 + tid * 8]);
      gload_lds16(gv + (size_t)(p * 32) * N_TOK + m0, &Vs[b][p * 2048 + tid * 8]);
    }
  };

  floatx4 o[4][4], l[4], zv;
#pragma unroll
  for (int r = 0; r < 4; ++r) zv[r] = 0.f;
#pragma unroll
  for (int qs = 0; qs < 4; ++qs) {
#pragma unroll
    for (int r = 0; r < 4; ++r) l[qs][r] = 0.f;
#pragma unroll
    for (int dt = 0; dt < 4; ++dt)
#pragma unroll
      for (int r = 0; r < 4; ++r) o[qs][dt][r] = 0.f;
  }

  short8 ones;
#pragma unroll
  for (int i = 0; i < 8; ++i) ones[i] = (short)0x3F80;  // bf16 1.0

  u16* psw = &Ps[wave][0];

  auto compute = [&](int b) __attribute__((always_inline)) {
    const u16* kbp = &Ks[b][0];
    const u16* vb  = &Vs[b][0];
#pragma unroll
    for (int kh = 0; kh < 2; ++kh) {
      // S^T for 32 k-rows (2 tiles) x 64 q, contraction d=64 (2 halves)
      short8 ak[2][2];
#pragma unroll
      for (int tl = 0; tl < 2; ++tl)
#pragma unroll
        for (int dh = 0; dh < 2; ++dh)
          ak[tl][dh] = *(const short8*)&kbp[((kh * 2 + tl) * 16 + l16) * 64
                                            + ((dh * 4 + quad) ^ r7) * 8];
#pragma unroll
      for (int qs = 0; qs < 4; ++qs) {
        floatx4 s0 = __builtin_amdgcn_mfma_f32_16x16x32_bf16(ak[0][0], bq[qs][0], zv, 0, 0, 0);
        floatx4 s1 = __builtin_amdgcn_mfma_f32_16x16x32_bf16(ak[1][0], bq[qs][0], zv, 0, 0, 0);
        s0 = __builtin_amdgcn_mfma_f32_16x16x32_bf16(ak[0][1], bq[qs][1], s0, 0, 0, 0);
        s1 = __builtin_amdgcn_mfma_f32_16x16x32_bf16(ak[1][1], bq[qs][1], s1, 0, 0, 0);
        // P~ = trunc_bf16(exp2(S)); store to wave-private P row q = qs*16+l16
        const int row = qs * 16 + l16;
        unsigned pa0 = permpack(aexp2(s0[0]), aexp2(s0[1]));
        unsigned pa1 = permpack(aexp2(s0[2]), aexp2(s0[3]));
        unsigned pb0 = permpack(aexp2(s1[0]), aexp2(s1[1]));
        unsigned pb1 = permpack(aexp2(s1[2]), aexp2(s1[3]));
        uint2v w0; w0[0] = pa0; w0[1] = pa1;
        uint2v w1; w1[0] = pb0; w1[1] = pb1;
        // tl=0: k_l = quad*4 -> chunk quad>>1 ; tl=1: k_l = 16+quad*4 -> chunk 2+(quad>>1)
        *(uint2v*)&psw[row * 32 + (((quad >> 1)) ^ r3) * 8 + (quad & 1) * 4]     = w0;
        *(uint2v*)&psw[row * 32 + ((2 + (quad >> 1)) ^ r3) * 8 + (quad & 1) * 4] = w1;
      }
      // PV for this k-half: A = P rows (wave-private, in-order DS => no barrier)
      short8 ap[4];
#pragma unroll
      for (int qs = 0; qs < 4; ++qs)
        ap[qs] = *(const short8*)&psw[(qs * 16 + l16) * 32 + ((quad ^ r3) * 8)];
#pragma unroll
      for (int dt = 0; dt < 4; ++dt) {
        short8 bv = *(const short8*)&vb[(dt * 16 + l16) * 64 + ((kh * 4 + quad) ^ r7) * 8];
#pragma unroll
        for (int qs = 0; qs < 4; ++qs)
          o[qs][dt] = __builtin_amdgcn_mfma_f32_16x16x32_bf16(ap[qs], bv, o[qs][dt], 0, 0, 0);
      }
#pragma unroll
      for (int qs = 0; qs < 4; ++qs)
        l[qs] = __builtin_amdgcn_mfma_f32_16x16x32_bf16(ap[qs], ones, l[qs], 0, 0, 0);
    }
  };

  stage(0, kb);
  __syncthreads();
  int m0 = kb + 64;
  for (int t = 1; t < nt; ++t) {
    stage(t & 1, m0);
    m0 += 64;
    compute((t - 1) & 1);
    __syncthreads();
  }
  compute((nt - 1) & 1);

  // write fp32 partials (combine kernel sums splits and normalizes)
  float* Ob = Opart + ((size_t)(split * H_NUM + h) * N_TOK) * 64;
  float* lb = lpart + (size_t)(split * H_NUM + h) * N_TOK;
#pragma unroll
  for (int qs = 0; qs < 4; ++qs) {
    const int rowg = qt * 256 + wave * 64 + qs * 16 + quad * 4;
#pragma unroll
    for (int r = 0; r < 4; ++r) {
#pragma unroll
      for (int dt = 0; dt < 4; ++dt)
        Ob[(size_t)(rowg + r) * 64 + dt * 16 + l16] = o[qs][dt][r];
      if (l16 == 0) lb[rowg + r] = l[qs][r];
    }
  }
}

// ---------------- combine split partials -> bf16 ao ----------------
__global__ void k_combine(const float* __restrict__ Op, const float* __restrict__ lp,
                          u16* __restrict__ ao) {
  const int idx = blockIdx.x * 256 + threadIdx.x;   // over 12*4096*64
  const int col = idx & 63;
  const int row = idx >> 6;                          // h*4096 + q
  float o = 0.f, l = 0.f;
#pragma unroll
  for (int s = 0; s < NSPL; ++s) {
    o += Op[((size_t)row + (size_t)s * H_NUM * N_TOK) * 64 + col];
    l += lp[row + s * H_NUM * N_TOK];
  }
  const int h = row >> 12, q = row & 4095;
  ao[(size_t)q * C_DIM + h * 64 + col] = f2bf(o * arcp(l));
}

extern "C" void kernel_launch(void* const* d_in, const int* in_sizes, int n_in,
                              void* d_out, int out_size, void* d_ws, size_t ws_size,
                              hipStream_t stream) {
  const float* x      = (const float*)d_in[0];
  const float* w_qkv  = (const float*)d_in[1];
  const float* b_qkv  = (const float*)d_in[2];
  const float* w_proj = (const float*)d_in[3];
  const float* b_proj = (const float*)d_in[4];
  float* out = (float*)d_out;

  u16* xb     = (u16*)d_ws;                          // [4096][768]
  u16* wqkvT  = xb     + (size_t)N_TOK * C_DIM;      // [2304][768]
  u16* wprojT = wqkvT  + (size_t)C3 * C_DIM;         // [768][768]
  u16* qkv    = wprojT + (size_t)C_DIM * C_DIM;      // [4096][2304] (q,k; q pre-scaled)
  u16* vT     = qkv    + (size_t)N_TOK * C3;         // [768][4096]
  u16* ao     = vT     + (size_t)C_DIM * N_TOK;      // [4096][768]
  float* Opart = (float*)(ao + (size_t)N_TOK * C_DIM); // [4][12][4096][64] fp32 (~50 MB)
  float* lpart = Opart + (size_t)NSPL * H_NUM * N_TOK * 64; // [4][12][4096]

  k_pre<<<5376, 256, 0, stream>>>(x, xb, w_qkv, wqkvT, w_proj, wprojT);
  k_gemm_bt<0><<<dim3(C3 / 128, N_TOK / 128), 256, 0, stream>>>(xb, wqkvT, b_qkv, qkv, vT, C_DIM);
  k_flash<<<dim3(N_TOK / 256, H_NUM, NSPL), 256, 0, stream>>>(qkv, vT, Opart, lpart);
  k_combine<<<H_NUM * N_TOK * 64 / 256, 256, 0, stream>>>(Opart, lpart, ao);
  k_gemm_bt<1><<<dim3(C_DIM / 128, N_TOK / 128), 256, 0, stream>>>(ao, wprojT, b_proj, out, nullptr, C_DIM);
}